// Round 8
// baseline (1813.536 us; speedup 1.0000x reference)
//
#include <hip/hip_runtime.h>
#include <stdint.h>

#define NN 4096
#define NSL 7
#define NITER 3
#define SEGB 8      // blocks per batch

typedef __attribute__((ext_vector_type(8))) short short8;
typedef __attribute__((ext_vector_type(4))) float f32x4;

__device__ __forceinline__ unsigned short f2bf(float f){
    union { float f; unsigned int i; } x; x.f = f;
    unsigned int u = x.i;
    u += 0x7fffu + ((u >> 16) & 1u);
    return (unsigned short)(u >> 16);
}
__device__ __forceinline__ unsigned int pack2(float a, float b){
    return (unsigned int)f2bf(a) | ((unsigned int)f2bf(b) << 16);
}
__device__ __forceinline__ short8 f2bf8(float4 a, float4 b){
    short8 r;
    r[0]=(short)f2bf(a.x); r[1]=(short)f2bf(a.y); r[2]=(short)f2bf(a.z); r[3]=(short)f2bf(a.w);
    r[4]=(short)f2bf(b.x); r[5]=(short)f2bf(b.y); r[6]=(short)f2bf(b.z); r[7]=(short)f2bf(b.w);
    return r;
}
__device__ __forceinline__ f32x4 mfma16(short8 a, short8 b, f32x4 c){
    return __builtin_amdgcn_mfma_f32_16x16x32_bf16(a, b, c, 0, 0, 0);
}
__device__ __forceinline__ float sigm(float x){ return 1.f / (1.f + __expf(-x)); }

__device__ __forceinline__ float dot64(const float* x, const float* w){
    float acc = 0.f;
    const float4* w4 = reinterpret_cast<const float4*>(w);
    #pragma unroll
    for (int e4 = 0; e4 < 16; ++e4){
        float4 wv = w4[e4];
        acc += x[e4*4+0]*wv.x + x[e4*4+1]*wv.y + x[e4*4+2]*wv.z + x[e4*4+3]*wv.w;
    }
    return acc;
}
__device__ __forceinline__ float dot128(const float* x, const float* w){
    float acc = 0.f;
    const float4* w4 = reinterpret_cast<const float4*>(w);
    #pragma unroll
    for (int e4 = 0; e4 < 32; ++e4){
        float4 wv = w4[e4];
        acc += x[e4*4+0]*wv.x + x[e4*4+1]*wv.y + x[e4*4+2]*wv.z + x[e4*4+3]*wv.w;
    }
    return acc;
}

struct FusedArgs {
    const float *inp, *g_in, *be_in, *Wk, *bk, *Wv, *bv;
    const float *W_ih, *W_hh, *b_ih, *b_hh, *W1, *b1, *W2, *b2;
    const float *g_sl, *be_sl, *g_ff, *be_ff, *Wq, *bq;
    float *slots_ws, *q_ws, *pu;
    int *ctr, *flag;
    float *out;
};

// ---------------------------------------------------------------------------
// Init: slots = mu + sigma*noise; LN_sl; q0. Also zeroes sync counters.
// ---------------------------------------------------------------------------
__global__ __launch_bounds__(256) void init_kernel(
    const float* __restrict__ noise, const float* __restrict__ mu,
    const float* __restrict__ sigma,
    const float* __restrict__ g_sl, const float* __restrict__ be_sl,
    const float* __restrict__ Wq, const float* __restrict__ bq,
    float* __restrict__ slots_ws, float* __restrict__ q_ws,
    int* __restrict__ ctr, int* __restrict__ flag)
{
    __shared__ float s2[NSL][64];
    const int t = threadIdx.x, lane = t & 63, wave = t >> 6;
    const int b = blockIdx.x;
    if (t < NITER) ctr[b*NITER + t] = 0;
    if (t == NITER) flag[b] = 0;
    for (int i = wave; i < NSL; i += 4){
        const long off = (long)(b*NSL + i)*64;
        float v = mu[lane] + sigma[lane]*noise[off + lane];
        slots_ws[off + lane] = v;
        float s = v, ss = v*v;
        #pragma unroll
        for (int m = 1; m < 64; m <<= 1){ s += __shfl_xor(s, m); ss += __shfl_xor(ss, m); }
        float mean = s * 0.015625f;
        float rstd = rsqrtf(ss * 0.015625f - mean*mean + 1e-5f);
        s2[i][lane] = (v - mean)*rstd*g_sl[lane] + be_sl[lane];
    }
    __syncthreads();
    for (int idx = t; idx < NSL*64; idx += 256){
        int i = idx >> 6, d = idx & 63;
        q_ws[(long)(b*NSL + i)*64 + d] = bq[d] + dot64(&s2[i][0], Wq + d*64);
    }
}

// ---------------------------------------------------------------------------
// Fused persistent kernel. 512 blocks (2/CU). Phase 0: LN+KV; k AND v frags
// captured into registers via small ping-pong LDS staging (46 KB total LDS).
// Then 3 iterations: dots/softmax/updates from registers, per-batch atomic
// sync, last-arriving block runs GRU/FF/q.
// ---------------------------------------------------------------------------
__global__ __launch_bounds__(256, 2) void fused_kernel(FusedArgs A)
{
    __shared__ __align__(16) unsigned short kstage[2][64*72];   // 2 x 9216 B
    __shared__ __align__(16) unsigned short vstage[2][64*72];   // 2 x 9216 B
    __shared__ __align__(16) unsigned char kat[4][2304];        // attn / red / reducer scratch
    __shared__ int bcast;

    const int t = threadIdx.x, lane = t & 63, wave = t >> 6;
    const int n16 = lane & 15, quad = lane >> 4;
    const int b = blockIdx.x >> 3, seg = blockIdx.x & 7;
    const long tok0 = (long)b * NN + seg * 512;

    // ================= phase 0: LN + K/V projection =================
    const float4 gA = *(const float4*)(A.g_in + quad*8);
    const float4 gB = *(const float4*)(A.g_in + quad*8 + 4);
    const float4 gC = *(const float4*)(A.g_in + 32 + quad*8);
    const float4 gD = *(const float4*)(A.g_in + 32 + quad*8 + 4);
    const float4 eA = *(const float4*)(A.be_in + quad*8);
    const float4 eB = *(const float4*)(A.be_in + quad*8 + 4);
    const float4 eC = *(const float4*)(A.be_in + 32 + quad*8);
    const float4 eD = *(const float4*)(A.be_in + 32 + quad*8 + 4);

    short8 wka0[4], wka1[4], wvb0[4], wvb1[4];
    float4 bk4[4]; float bvs[4];
    #pragma unroll
    for (int mt = 0; mt < 4; ++mt){
        const float* wp = A.Wk + (mt*16 + n16)*64 + quad*8;
        wka0[mt] = f2bf8(*(const float4*)(wp),      *(const float4*)(wp + 4));
        wka1[mt] = f2bf8(*(const float4*)(wp + 32), *(const float4*)(wp + 36));
        const float* vp = A.Wv + (mt*16 + n16)*64 + quad*8;
        wvb0[mt] = f2bf8(*(const float4*)(vp),      *(const float4*)(vp + 4));
        wvb1[mt] = f2bf8(*(const float4*)(vp + 32), *(const float4*)(vp + 36));
        bk4[mt] = *(const float4*)(A.bk + mt*16 + quad*4);
        bvs[mt] = A.bv[mt*16 + n16];
    }

    short8 kb[2][4][2];   // k B-frags: [h][token-tile][feature-half]
    short8 vf[2][4][2];   // v B-frags: [h][d-tile][token-half]

    #pragma unroll
    for (int c = 0; c < 8; ++c){
        const int buf = c & 1;
        const float* rp = A.inp + (tok0 + c*64 + wave*16 + n16) * 64;
        float4 xa = *(const float4*)(rp + quad*8);
        float4 xb = *(const float4*)(rp + quad*8 + 4);
        float4 xc = *(const float4*)(rp + 32 + quad*8);
        float4 xd = *(const float4*)(rp + 32 + quad*8 + 4);

        float s  = (xa.x+xa.y+xa.z+xa.w) + (xb.x+xb.y+xb.z+xb.w)
                 + (xc.x+xc.y+xc.z+xc.w) + (xd.x+xd.y+xd.z+xd.w);
        float ss = (xa.x*xa.x+xa.y*xa.y+xa.z*xa.z+xa.w*xa.w)
                 + (xb.x*xb.x+xb.y*xb.y+xb.z*xb.z+xb.w*xb.w)
                 + (xc.x*xc.x+xc.y*xc.y+xc.z*xc.z+xc.w*xc.w)
                 + (xd.x*xd.x+xd.y*xd.y+xd.z*xd.z+xd.w*xd.w);
        s  += __shfl_xor(s, 16);  ss += __shfl_xor(ss, 16);
        s  += __shfl_xor(s, 32);  ss += __shfl_xor(ss, 32);
        const float mean = s * 0.015625f;
        const float rstd = rsqrtf(ss * 0.015625f - mean*mean + 1e-5f);
        float4 ya, yb, yc, yd;
        ya.x=(xa.x-mean)*rstd*gA.x+eA.x; ya.y=(xa.y-mean)*rstd*gA.y+eA.y;
        ya.z=(xa.z-mean)*rstd*gA.z+eA.z; ya.w=(xa.w-mean)*rstd*gA.w+eA.w;
        yb.x=(xb.x-mean)*rstd*gB.x+eB.x; yb.y=(xb.y-mean)*rstd*gB.y+eB.y;
        yb.z=(xb.z-mean)*rstd*gB.z+eB.z; yb.w=(xb.w-mean)*rstd*gB.w+eB.w;
        yc.x=(xc.x-mean)*rstd*gC.x+eC.x; yc.y=(xc.y-mean)*rstd*gC.y+eC.y;
        yc.z=(xc.z-mean)*rstd*gC.z+eC.z; yc.w=(xc.w-mean)*rstd*gC.w+eC.w;
        yd.x=(xd.x-mean)*rstd*gD.x+eD.x; yd.y=(xd.y-mean)*rstd*gD.y+eD.y;
        yd.z=(xd.z-mean)*rstd*gD.z+eD.z; yd.w=(xd.w-mean)*rstd*gD.w+eD.w;
        const short8 xf0 = f2bf8(ya, yb);
        const short8 xf1 = f2bf8(yc, yd);

        // k = Wk·xn^T -> kstage[token][feature]
        #pragma unroll
        for (int mt = 0; mt < 4; ++mt){
            f32x4 z = {0.f,0.f,0.f,0.f};
            z = mfma16(wka0[mt], xf0, z);
            z = mfma16(wka1[mt], xf1, z);
            uint2 pk;
            pk.x = pack2(z[0]+bk4[mt].x, z[1]+bk4[mt].y);
            pk.y = pack2(z[2]+bk4[mt].z, z[3]+bk4[mt].w);
            *(uint2*)(&kstage[buf][(wave*16 + n16)*72 + mt*16 + quad*4]) = pk;
        }
        // v = xn·Wv^T -> vstage[d][token]
        #pragma unroll
        for (int dt = 0; dt < 4; ++dt){
            f32x4 z = {0.f,0.f,0.f,0.f};
            z = mfma16(xf0, wvb0[dt], z);
            z = mfma16(xf1, wvb1[dt], z);
            uint2 pk;
            pk.x = pack2(z[0]+bvs[dt], z[1]+bvs[dt]);
            pk.y = pack2(z[2]+bvs[dt], z[3]+bvs[dt]);
            *(uint2*)(&vstage[buf][(dt*16 + n16)*72 + wave*16 + quad*4]) = pk;
        }
        __syncthreads();
        if (wave == (c >> 1)){
            const int h = c & 1;
            #pragma unroll
            for (int tt = 0; tt < 4; ++tt){
                kb[h][tt][0] = *(const short8*)(&kstage[buf][(tt*16 + n16)*72 + quad*8]);
                kb[h][tt][1] = *(const short8*)(&kstage[buf][(tt*16 + n16)*72 + 32 + quad*8]);
            }
            #pragma unroll
            for (int t2 = 0; t2 < 4; ++t2){
                vf[h][t2][0] = *(const short8*)(&vstage[buf][(t2*16 + n16)*72 + quad*8]);
                vf[h][t2][1] = *(const short8*)(&vstage[buf][(t2*16 + n16)*72 + 32 + quad*8]);
            }
        }
        // no trailing barrier: next tile writes buf^1; same buf rewritten only
        // after the NEXT __syncthreads, by which time these reads are drained.
    }

    // ================= iterations =================
    short8 ones;
    { const short ov = (n16 == 0) ? (short)0x3F80 : (short)0;
      #pragma unroll
      for (int z = 0; z < 8; ++z) ones[z] = ov; }

    for (int it = 0; it < NITER; ++it){
        if (it > 0){
            if (t == 0){
                while (__hip_atomic_load(A.flag + b, __ATOMIC_ACQUIRE, __HIP_MEMORY_SCOPE_AGENT) < it)
                    __builtin_amdgcn_s_sleep(2);
            }
            __syncthreads();
            __threadfence();
        }
        const int iq = (n16 < NSL) ? n16 : (NSL - 1);
        const float* qp = A.q_ws + (b*NSL + iq)*64;
        float4 q0 = *(const float4*)(qp + quad*8);
        float4 q1 = *(const float4*)(qp + quad*8 + 4);
        float4 q2 = *(const float4*)(qp + 32 + quad*8);
        float4 q3 = *(const float4*)(qp + 32 + quad*8 + 4);
        short8 qa0 = f2bf8(make_float4(q0.x*0.125f,q0.y*0.125f,q0.z*0.125f,q0.w*0.125f),
                           make_float4(q1.x*0.125f,q1.y*0.125f,q1.z*0.125f,q1.w*0.125f));
        short8 qa1 = f2bf8(make_float4(q2.x*0.125f,q2.y*0.125f,q2.z*0.125f,q2.w*0.125f),
                           make_float4(q3.x*0.125f,q3.y*0.125f,q3.z*0.125f,q3.w*0.125f));

        unsigned short* at = (unsigned short*)&kat[wave][0];
        for (int idx = lane; idx < 9*72; idx += 64){
            int rr = idx / 72, cc2 = idx - rr*72;
            at[(7 + rr)*72 + cc2] = (rr == 0 && cc2 < 64) ? (unsigned short)0x3F80 : (unsigned short)0;
        }
        f32x4 uacc[5];
        #pragma unroll
        for (int z = 0; z < 5; ++z){ f32x4 zz = {0.f,0.f,0.f,0.f}; uacc[z] = zz; }

        #pragma unroll
        for (int h = 0; h < 2; ++h){
            #pragma unroll
            for (int tt = 0; tt < 4; ++tt){
                f32x4 dz = {0.f,0.f,0.f,0.f};
                dz = mfma16(qa0, kb[h][tt][0], dz);
                dz = mfma16(qa1, kb[h][tt][1], dz);
                float pm;
                if (quad == 0)      pm = fmaxf(fmaxf(dz[0], dz[1]), fmaxf(dz[2], dz[3]));
                else if (quad == 1) pm = fmaxf(fmaxf(dz[0], dz[1]), dz[2]);
                else                pm = -1e30f;
                pm = fmaxf(pm, __shfl_xor(pm, 16));
                float e0=0.f, e1=0.f, e2=0.f, e3=0.f;
                if (quad == 0){ e0=__expf(dz[0]-pm); e1=__expf(dz[1]-pm); e2=__expf(dz[2]-pm); e3=__expf(dz[3]-pm); }
                else if (quad == 1){ e0=__expf(dz[0]-pm); e1=__expf(dz[1]-pm); e2=__expf(dz[2]-pm); }
                float ps = e0 + e1 + e2 + e3;
                ps += __shfl_xor(ps, 16);
                const float inv = 1.f / ps;
                if (quad == 0){
                    at[0*72 + tt*16 + n16] = f2bf(e0*inv);
                    at[1*72 + tt*16 + n16] = f2bf(e1*inv);
                    at[2*72 + tt*16 + n16] = f2bf(e2*inv);
                    at[3*72 + tt*16 + n16] = f2bf(e3*inv);
                } else if (quad == 1){
                    at[4*72 + tt*16 + n16] = f2bf(e0*inv);
                    at[5*72 + tt*16 + n16] = f2bf(e1*inv);
                    at[6*72 + tt*16 + n16] = f2bf(e2*inv);
                }
            }
            // wave-private LDS, in-order within wave: no barrier needed
            short8 aa0 = *(const short8*)(at + n16*72 + quad*8);
            short8 aa1 = *(const short8*)(at + n16*72 + 32 + quad*8);
            #pragma unroll
            for (int t2 = 0; t2 < 4; ++t2){
                uacc[t2] = mfma16(aa0, vf[h][t2][0], uacc[t2]);
                uacc[t2] = mfma16(aa1, vf[h][t2][1], uacc[t2]);
            }
            uacc[4] = mfma16(aa0, ones, uacc[4]);
            uacc[4] = mfma16(aa1, ones, uacc[4]);
        }
        __syncthreads();   // all attn LDS traffic done before red overlay
        float* redw = (float*)&kat[wave][0];   // [8][72] f32
        if (quad < 2){
            #pragma unroll
            for (int r = 0; r < 4; ++r){
                const int i = quad*4 + r;
                #pragma unroll
                for (int t2 = 0; t2 < 5; ++t2)
                    if (t2 < 4 || n16 == 0) redw[i*72 + t2*16 + n16] = uacc[t2][r];
            }
        }
        __syncthreads();
        {
            const float* r0 = (const float*)&kat[0][0];
            const float* r1 = (const float*)&kat[1][0];
            const float* r2 = (const float*)&kat[2][0];
            const float* r3 = (const float*)&kat[3][0];
            float* pb = A.pu + (long)(b*SEGB + seg)*8*72;
            for (int idx = t; idx < 8*72; idx += 256)
                pb[idx] = r0[idx] + r1[idx] + r2[idx] + r3[idx];
        }
        __threadfence();
        if (t == 0) bcast = atomicAdd(A.ctr + b*NITER + it, 1);
        __syncthreads();
        const bool reducer = (bcast == SEGB - 1);
        if (reducer){
            __threadfence();
            float* ws = (float*)&kat[wave][0];  // upd[0..63] hpr[64..] ffb[128..] h1[192..319] s2[320..383]
            for (int i = wave; i < NSL; i += 4){
                float si = 0.f, s7 = 0.f;
                #pragma unroll
                for (int u = 0; u < SEGB; ++u){
                    const float* base = A.pu + (long)(b*SEGB + u)*8*72;
                    si += base[i*72 + lane];
                    s7 += base[7*72 + lane];
                }
                float ap = (lane < SEGB) ? A.pu[(long)(b*SEGB + lane)*8*72 + i*72 + 64] : 0.f;
                #pragma unroll
                for (int m = 1; m < 64; m <<= 1) ap += __shfl_xor(ap, m);
                const float updd = (si + 1e-8f*s7) / (ap + 4.096e-5f);
                const float hprd = A.slots_ws[(b*NSL + i)*64 + lane];
                ws[lane] = updd; ws[64 + lane] = hprd;
                float gi0 = A.b_ih[lane]     + dot64(ws,    A.W_ih + lane*64);
                float gi1 = A.b_ih[64+lane]  + dot64(ws,    A.W_ih + (64+lane)*64);
                float gi2 = A.b_ih[128+lane] + dot64(ws,    A.W_ih + (128+lane)*64);
                float gh0 = A.b_hh[lane]     + dot64(ws+64, A.W_hh + lane*64);
                float gh1 = A.b_hh[64+lane]  + dot64(ws+64, A.W_hh + (64+lane)*64);
                float gh2 = A.b_hh[128+lane] + dot64(ws+64, A.W_hh + (128+lane)*64);
                float rg = sigm(gi0 + gh0);
                float zg = sigm(gi1 + gh1);
                float ng = tanhf(gi2 + rg*gh2);
                float sn = (1.f - zg)*ng + zg*hprd;
                float s = sn, ssq = sn*sn;
                #pragma unroll
                for (int m = 1; m < 64; m <<= 1){ s += __shfl_xor(s, m); ssq += __shfl_xor(ssq, m); }
                float mean = s * 0.015625f;
                float rstd = rsqrtf(ssq * 0.015625f - mean*mean + 1e-5f);
                float ffd = (sn - mean)*rstd*A.g_ff[lane] + A.be_ff[lane];
                ws[128 + lane] = ffd;
                float ha = A.b1[lane]    + dot64(ws+128, A.W1 + lane*64);
                float hb = A.b1[64+lane] + dot64(ws+128, A.W1 + (64+lane)*64);
                ws[192 + lane] = ha > 0.f ? ha : 0.f;
                ws[256 + lane] = hb > 0.f ? hb : 0.f;
                float o = A.b2[lane] + dot128(ws+192, A.W2 + lane*128);
                float sf = sn + o;
                A.slots_ws[(b*NSL + i)*64 + lane] = sf;
                if (it == NITER-1){
                    A.out[(b*NSL + i)*64 + lane] = sf;
                } else {
                    float s2v = sf, ss2 = sf*sf;
                    #pragma unroll
                    for (int m = 1; m < 64; m <<= 1){ s2v += __shfl_xor(s2v, m); ss2 += __shfl_xor(ss2, m); }
                    float mean2 = s2v * 0.015625f;
                    float rstd2 = rsqrtf(ss2 * 0.015625f - mean2*mean2 + 1e-5f);
                    float s2d = (sf - mean2)*rstd2*A.g_sl[lane] + A.be_sl[lane];
                    ws[320 + lane] = s2d;
                    A.q_ws[(b*NSL + i)*64 + lane] = A.bq[lane] + dot64(ws+320, A.Wq + lane*64);
                }
            }
            __syncthreads();
            __threadfence();
            if (t == 0 && it < NITER-1)
                __hip_atomic_store(A.flag + b, it+1, __ATOMIC_RELEASE, __HIP_MEMORY_SCOPE_AGENT);
        }
        __syncthreads();
    }
}

// ---------------------------------------------------------------------------
extern "C" void kernel_launch(void* const* d_in, const int* in_sizes, int n_in,
                              void* d_out, int out_size, void* d_ws, size_t ws_size,
                              hipStream_t stream)
{
    const float* inp   = (const float*)d_in[0];
    const float* noise = (const float*)d_in[2];
    const float* mu    = (const float*)d_in[3];
    const float* sigma = (const float*)d_in[4];
    const float* Wq    = (const float*)d_in[5];
    const float* bq    = (const float*)d_in[6];
    const float* Wk    = (const float*)d_in[7];
    const float* bk    = (const float*)d_in[8];
    const float* Wv    = (const float*)d_in[9];
    const float* bv    = (const float*)d_in[10];
    const float* W_ih  = (const float*)d_in[11];
    const float* W_hh  = (const float*)d_in[12];
    const float* b_ih  = (const float*)d_in[13];
    const float* b_hh  = (const float*)d_in[14];
    const float* W1    = (const float*)d_in[15];
    const float* b1    = (const float*)d_in[16];
    const float* W2    = (const float*)d_in[17];
    const float* b2    = (const float*)d_in[18];
    const float* g_in  = (const float*)d_in[19];
    const float* be_in = (const float*)d_in[20];
    const float* g_sl  = (const float*)d_in[21];
    const float* be_sl = (const float*)d_in[22];
    const float* g_ff  = (const float*)d_in[23];
    const float* be_ff = (const float*)d_in[24];
    float* out = (float*)d_out;

    char* w = (char*)d_ws;
    float* slots_ws = (float*)(w);                     // 114,688 B
    float* q_ws     = (float*)(w + 114688);            // 114,688 B
    float* pu       = (float*)(w + 229376);            // 64*8*8*72*4 = 1,179,648 B
    int*   ctr      = (int*)  (w + 1409024);           // 768 B
    int*   flag     = (int*)  (w + 1409792);           // 256 B

    init_kernel<<<64, 256, 0, stream>>>(noise, mu, sigma, g_sl, be_sl, Wq, bq,
                                        slots_ws, q_ws, ctr, flag);

    FusedArgs fa;
    fa.inp = inp; fa.g_in = g_in; fa.be_in = be_in;
    fa.Wk = Wk; fa.bk = bk; fa.Wv = Wv; fa.bv = bv;
    fa.W_ih = W_ih; fa.W_hh = W_hh; fa.b_ih = b_ih; fa.b_hh = b_hh;
    fa.W1 = W1; fa.b1 = b1; fa.W2 = W2; fa.b2 = b2;
    fa.g_sl = g_sl; fa.be_sl = be_sl; fa.g_ff = g_ff; fa.be_ff = be_ff;
    fa.Wq = Wq; fa.bq = bq;
    fa.slots_ws = slots_ws; fa.q_ws = q_ws; fa.pu = pu;
    fa.ctr = ctr; fa.flag = flag; fa.out = out;

    void* kargs[] = { (void*)&fa };
    hipError_t e = hipLaunchCooperativeKernel((const void*)fused_kernel,
                                              dim3(512), dim3(256), kargs, 0, stream);
    if (e != hipSuccess){
        // fallback: plain launch (512 blocks at 2/CU fit the 256-CU device)
        fused_kernel<<<512, 256, 0, stream>>>(fa);
    }
}

// Round 9
// 829.294 us; speedup vs baseline: 2.1868x; 2.1868x over previous
//
#include <hip/hip_runtime.h>
#include <stdint.h>

#define NN 4096
#define NSL 7
#define NITER 3
#define SEGB 8       // blocks per batch
#define WSLOT 32     // wave-slots per batch (SEGB*4)

typedef __attribute__((ext_vector_type(8))) short short8;
typedef __attribute__((ext_vector_type(4))) float f32x4;

__device__ __forceinline__ unsigned short f2bf(float f){
    union { float f; unsigned int i; } x; x.f = f;
    unsigned int u = x.i;
    u += 0x7fffu + ((u >> 16) & 1u);
    return (unsigned short)(u >> 16);
}
__device__ __forceinline__ unsigned int pack2(float a, float b){
    return (unsigned int)f2bf(a) | ((unsigned int)f2bf(b) << 16);
}
__device__ __forceinline__ short8 f2bf8(float4 a, float4 b){
    short8 r;
    r[0]=(short)f2bf(a.x); r[1]=(short)f2bf(a.y); r[2]=(short)f2bf(a.z); r[3]=(short)f2bf(a.w);
    r[4]=(short)f2bf(b.x); r[5]=(short)f2bf(b.y); r[6]=(short)f2bf(b.z); r[7]=(short)f2bf(b.w);
    return r;
}
__device__ __forceinline__ f32x4 mfma16(short8 a, short8 b, f32x4 c){
    return __builtin_amdgcn_mfma_f32_16x16x32_bf16(a, b, c, 0, 0, 0);
}
__device__ __forceinline__ float sigm(float x){ return 1.f / (1.f + __expf(-x)); }

__device__ __forceinline__ float dot64(const float* x, const float* w){
    float acc = 0.f;
    const float4* w4 = reinterpret_cast<const float4*>(w);
    #pragma unroll
    for (int e4 = 0; e4 < 16; ++e4){
        float4 wv = w4[e4];
        acc += x[e4*4+0]*wv.x + x[e4*4+1]*wv.y + x[e4*4+2]*wv.z + x[e4*4+3]*wv.w;
    }
    return acc;
}
__device__ __forceinline__ float dot128(const float* x, const float* w){
    float acc = 0.f;
    const float4* w4 = reinterpret_cast<const float4*>(w);
    #pragma unroll
    for (int e4 = 0; e4 < 32; ++e4){
        float4 wv = w4[e4];
        acc += x[e4*4+0]*wv.x + x[e4*4+1]*wv.y + x[e4*4+2]*wv.z + x[e4*4+3]*wv.w;
    }
    return acc;
}

struct FusedArgs {
    const float *inp, *g_in, *be_in, *Wk, *bk, *Wv, *bv;
    const float *noise, *mu, *sigma;
    const float *W_ih, *W_hh, *b_ih, *b_hh, *W1, *b1, *W2, *b2;
    const float *g_sl, *be_sl, *g_ff, *be_ff, *Wq, *bq;
    float *pu;
    int *ctr;
    float *out;
};

// ---------------------------------------------------------------------------
// Fully fused persistent kernel. 512 blocks (2/CU, co-resident).
//  Phase 0 (barrier-free): each wave LN+projects its own 128 tokens; k/v
//  fragments captured to registers via WAVE-PRIVATE LDS staging.
//  Per iteration: dots/softmax/updates from registers -> per-wave partials to
//  pu -> release-RMW arrival counter -> relaxed-RMW poll (coherent-point, no
//  L2-invalidate storm) -> one acquire -> EVERY block redundantly computes
//  GRU/FF/q for its batch (slots/q in block LDS). seg==0 writes out.
// ---------------------------------------------------------------------------
__global__ __launch_bounds__(256, 2) void fused_kernel(FusedArgs A)
{
    __shared__ __align__(16) unsigned short kst[4][16*72];   // per-wave k group staging
    __shared__ __align__(16) unsigned short vst[4][64*40];   // per-wave v chunk staging
    __shared__ __align__(16) unsigned short at_s[4][16*40];  // per-wave attn chunk [slot][32 tok]
    __shared__ float ws_s[4][384];                           // per-wave GRU scratch
    __shared__ float qsh[NSL][68];                           // padded pitch (bank spread)
    __shared__ float slotsb[NSL][64];

    const int t = threadIdx.x, lane = t & 63, wave = t >> 6;
    const int n16 = lane & 15, quad = lane >> 4;
    const int b = blockIdx.x >> 3, seg = blockIdx.x & 7;
    const long T0w = (long)b * NN + seg * 512 + wave * 128;

    // ---------------- phase 0: LN + K/V into registers ----------------
    const float4 gA = *(const float4*)(A.g_in + quad*8);
    const float4 gB = *(const float4*)(A.g_in + quad*8 + 4);
    const float4 gC = *(const float4*)(A.g_in + 32 + quad*8);
    const float4 gD = *(const float4*)(A.g_in + 32 + quad*8 + 4);
    const float4 eA = *(const float4*)(A.be_in + quad*8);
    const float4 eB = *(const float4*)(A.be_in + quad*8 + 4);
    const float4 eC = *(const float4*)(A.be_in + 32 + quad*8);
    const float4 eD = *(const float4*)(A.be_in + 32 + quad*8 + 4);

    short8 wka0[4], wka1[4], wvb0[4], wvb1[4];
    float4 bk4[4]; float bvs[4];
    #pragma unroll
    for (int mt = 0; mt < 4; ++mt){
        const float* wp = A.Wk + (mt*16 + n16)*64 + quad*8;
        wka0[mt] = f2bf8(*(const float4*)(wp),      *(const float4*)(wp + 4));
        wka1[mt] = f2bf8(*(const float4*)(wp + 32), *(const float4*)(wp + 36));
        const float* vp = A.Wv + (mt*16 + n16)*64 + quad*8;
        wvb0[mt] = f2bf8(*(const float4*)(vp),      *(const float4*)(vp + 4));
        wvb1[mt] = f2bf8(*(const float4*)(vp + 32), *(const float4*)(vp + 36));
        bk4[mt] = *(const float4*)(A.bk + mt*16 + quad*4);
        bvs[mt] = A.bv[mt*16 + n16];
    }

    unsigned short* kw = &kst[wave][0];
    unsigned short* vw = &vst[wave][0];
    short8 kb[8][2];    // k B-frags per 16-token group
    short8 vf[4][4];    // v B-frags per 32-token chunk x 4 d-tiles

    float4 Xc0, Xc1, Xc2, Xc3;
    {
        const float* rp = A.inp + (T0w + n16) * 64;
        Xc0 = *(const float4*)(rp + quad*8);
        Xc1 = *(const float4*)(rp + quad*8 + 4);
        Xc2 = *(const float4*)(rp + 32 + quad*8);
        Xc3 = *(const float4*)(rp + 32 + quad*8 + 4);
    }
    #pragma unroll
    for (int g = 0; g < 8; ++g){
        float4 Xn0, Xn1, Xn2, Xn3;
        if (g + 1 < 8){
            const float* rp = A.inp + (T0w + (g+1)*16 + n16) * 64;
            Xn0 = *(const float4*)(rp + quad*8);
            Xn1 = *(const float4*)(rp + quad*8 + 4);
            Xn2 = *(const float4*)(rp + 32 + quad*8);
            Xn3 = *(const float4*)(rp + 32 + quad*8 + 4);
        }
        float4 xa = Xc0, xb = Xc1, xc = Xc2, xd = Xc3;
        float s  = (xa.x+xa.y+xa.z+xa.w) + (xb.x+xb.y+xb.z+xb.w)
                 + (xc.x+xc.y+xc.z+xc.w) + (xd.x+xd.y+xd.z+xd.w);
        float ss = (xa.x*xa.x+xa.y*xa.y+xa.z*xa.z+xa.w*xa.w)
                 + (xb.x*xb.x+xb.y*xb.y+xb.z*xb.z+xb.w*xb.w)
                 + (xc.x*xc.x+xc.y*xc.y+xc.z*xc.z+xc.w*xc.w)
                 + (xd.x*xd.x+xd.y*xd.y+xd.z*xd.z+xd.w*xd.w);
        s  += __shfl_xor(s, 16);  ss += __shfl_xor(ss, 16);
        s  += __shfl_xor(s, 32);  ss += __shfl_xor(ss, 32);
        const float mean = s * 0.015625f;
        const float rstd = rsqrtf(ss * 0.015625f - mean*mean + 1e-5f);
        float4 ya, yb, yc, yd;
        ya.x=(xa.x-mean)*rstd*gA.x+eA.x; ya.y=(xa.y-mean)*rstd*gA.y+eA.y;
        ya.z=(xa.z-mean)*rstd*gA.z+eA.z; ya.w=(xa.w-mean)*rstd*gA.w+eA.w;
        yb.x=(xb.x-mean)*rstd*gB.x+eB.x; yb.y=(xb.y-mean)*rstd*gB.y+eB.y;
        yb.z=(xb.z-mean)*rstd*gB.z+eB.z; yb.w=(xb.w-mean)*rstd*gB.w+eB.w;
        yc.x=(xc.x-mean)*rstd*gC.x+eC.x; yc.y=(xc.y-mean)*rstd*gC.y+eC.y;
        yc.z=(xc.z-mean)*rstd*gC.z+eC.z; yc.w=(xc.w-mean)*rstd*gC.w+eC.w;
        yd.x=(xd.x-mean)*rstd*gD.x+eD.x; yd.y=(xd.y-mean)*rstd*gD.y+eD.y;
        yd.z=(xd.z-mean)*rstd*gD.z+eD.z; yd.w=(xd.w-mean)*rstd*gD.w+eD.w;
        const short8 xf0 = f2bf8(ya, yb);
        const short8 xf1 = f2bf8(yc, yd);

        // k = Wk·xn^T -> kw[token n16][feature]
        #pragma unroll
        for (int mt = 0; mt < 4; ++mt){
            f32x4 z = {0.f,0.f,0.f,0.f};
            z = mfma16(wka0[mt], xf0, z);
            z = mfma16(wka1[mt], xf1, z);
            uint2 pk;
            pk.x = pack2(z[0]+bk4[mt].x, z[1]+bk4[mt].y);
            pk.y = pack2(z[2]+bk4[mt].z, z[3]+bk4[mt].w);
            *(uint2*)(kw + n16*72 + mt*16 + quad*4) = pk;
        }
        // v = xn·Wv^T -> vw[d][token-in-chunk]
        #pragma unroll
        for (int dt = 0; dt < 4; ++dt){
            f32x4 z = {0.f,0.f,0.f,0.f};
            z = mfma16(xf0, wvb0[dt], z);
            z = mfma16(xf1, wvb1[dt], z);
            uint2 pk;
            pk.x = pack2(z[0]+bvs[dt], z[1]+bvs[dt]);
            pk.y = pack2(z[2]+bvs[dt], z[3]+bvs[dt]);
            *(uint2*)(vw + (dt*16 + n16)*40 + (g&1)*16 + quad*4) = pk;
        }
        // wave-private LDS, in-order: extract fragments, no barrier
        kb[g][0] = *(const short8*)(kw + n16*72 + quad*8);
        kb[g][1] = *(const short8*)(kw + n16*72 + 32 + quad*8);
        if (g & 1){
            const int c2 = g >> 1;
            #pragma unroll
            for (int t2 = 0; t2 < 4; ++t2)
                vf[c2][t2] = *(const short8*)(vw + (t2*16 + n16)*40 + quad*8);
        }
        Xc0 = Xn0; Xc1 = Xn1; Xc2 = Xn2; Xc3 = Xn3;
    }

    // ---------------- init slots + q0 (block-local, redundant per block) ----
    unsigned short* at = &at_s[wave][0];
    float* ws = &ws_s[wave][0];
    for (int i = wave; i < NSL; i += 4){
        const long off = (long)(b*NSL + i)*64;
        float v = A.mu[lane] + A.sigma[lane]*A.noise[off + lane];
        slotsb[i][lane] = v;
        float s = v, ss = v*v;
        #pragma unroll
        for (int m = 1; m < 64; m <<= 1){ s += __shfl_xor(s, m); ss += __shfl_xor(ss, m); }
        float mean = s * 0.015625f;
        float rstd = rsqrtf(ss * 0.015625f - mean*mean + 1e-5f);
        ws[lane] = (v - mean)*rstd*A.g_sl[lane] + A.be_sl[lane];
        qsh[i][lane] = A.bq[lane] + dot64(ws, A.Wq + lane*64);
    }
    if (lane < 32) at[7*40 + lane] = (unsigned short)0x3F80;   // ones row for vsum
    __syncthreads();

    short8 ones;
    { const short ov = (n16 == 0) ? (short)0x3F80 : (short)0;
      #pragma unroll
      for (int z = 0; z < 8; ++z) ones[z] = ov; }

    // ---------------- iterations ----------------
    for (int it = 0; it < NITER; ++it){
        // q fragments from block LDS
        const int iq = (n16 < NSL) ? n16 : (NSL - 1);
        const float* qp = &qsh[iq][0];
        float4 q0 = *(const float4*)(qp + quad*8);
        float4 q1 = *(const float4*)(qp + quad*8 + 4);
        float4 q2 = *(const float4*)(qp + 32 + quad*8);
        float4 q3 = *(const float4*)(qp + 32 + quad*8 + 4);
        short8 qa0 = f2bf8(make_float4(q0.x*0.125f,q0.y*0.125f,q0.z*0.125f,q0.w*0.125f),
                           make_float4(q1.x*0.125f,q1.y*0.125f,q1.z*0.125f,q1.w*0.125f));
        short8 qa1 = f2bf8(make_float4(q2.x*0.125f,q2.y*0.125f,q2.z*0.125f,q2.w*0.125f),
                           make_float4(q3.x*0.125f,q3.y*0.125f,q3.z*0.125f,q3.w*0.125f));

        f32x4 uacc[5];
        #pragma unroll
        for (int z = 0; z < 5; ++z){ f32x4 zz = {0.f,0.f,0.f,0.f}; uacc[z] = zz; }

        #pragma unroll
        for (int g = 0; g < 8; ++g){
            f32x4 dz = {0.f,0.f,0.f,0.f};
            dz = mfma16(qa0, kb[g][0], dz);
            dz = mfma16(qa1, kb[g][1], dz);
            float pm;
            if (quad == 0)      pm = fmaxf(fmaxf(dz[0], dz[1]), fmaxf(dz[2], dz[3]));
            else if (quad == 1) pm = fmaxf(fmaxf(dz[0], dz[1]), dz[2]);
            else                pm = -1e30f;
            pm = fmaxf(pm, __shfl_xor(pm, 16));
            float e0=0.f, e1=0.f, e2=0.f, e3=0.f;
            if (quad == 0){ e0=__expf(dz[0]-pm); e1=__expf(dz[1]-pm); e2=__expf(dz[2]-pm); e3=__expf(dz[3]-pm); }
            else if (quad == 1){ e0=__expf(dz[0]-pm); e1=__expf(dz[1]-pm); e2=__expf(dz[2]-pm); }
            float ps = e0 + e1 + e2 + e3;
            ps += __shfl_xor(ps, 16);
            const float inv = 1.f / ps;
            const int col = (g&1)*16 + n16;
            if (quad == 0){
                at[0*40 + col] = f2bf(e0*inv);
                at[1*40 + col] = f2bf(e1*inv);
                at[2*40 + col] = f2bf(e2*inv);
                at[3*40 + col] = f2bf(e3*inv);
            } else if (quad == 1){
                at[4*40 + col] = f2bf(e0*inv);
                at[5*40 + col] = f2bf(e1*inv);
                at[6*40 + col] = f2bf(e2*inv);
            }
            if (g & 1){
                const int c2 = g >> 1;
                short8 aa = *(const short8*)(at + n16*40 + quad*8);
                #pragma unroll
                for (int t2 = 0; t2 < 4; ++t2)
                    uacc[t2] = mfma16(aa, vf[c2][t2], uacc[t2]);
                uacc[4] = mfma16(aa, ones, uacc[4]);
            }
        }

        // per-wave partials -> pu[b][seg*4+wave][8 rows][72]
        float* pb = A.pu + ((long)(b*WSLOT + seg*4 + wave) * 8) * 72;
        if (quad < 2){
            #pragma unroll
            for (int r = 0; r < 4; ++r){
                const int i = quad*4 + r;
                #pragma unroll
                for (int t2 = 0; t2 < 4; ++t2)
                    pb[i*72 + t2*16 + n16] = uacc[t2][r];
                if (n16 == 0) pb[i*72 + 64] = uacc[4][r];
            }
        }

        // arrival (release folds in writeback of the pu stores above)
        int* cp = A.ctr + b*NITER + it;
        if (lane == 0)
            __hip_atomic_fetch_add(cp, 1, __ATOMIC_RELEASE, __HIP_MEMORY_SCOPE_AGENT);
        // relaxed RMW poll at the coherent point (no per-poll L2 invalidate)
        int v = 0; int guard = 0;
        do {
            if (lane == 0)
                v = __hip_atomic_fetch_add(cp, 0, __ATOMIC_RELAXED, __HIP_MEMORY_SCOPE_AGENT);
            v = __shfl(v, 0);
            if (v < WSLOT) __builtin_amdgcn_s_sleep(8);
        } while (v < WSLOT && ++guard < (1<<25));
        __hip_atomic_load(cp, __ATOMIC_ACQUIRE, __HIP_MEMORY_SCOPE_AGENT);  // one inv

        // redundant per-block GRU/FF/q for this batch
        for (int i = wave; i < NSL; i += 4){
            float si = 0.f, s7 = 0.f;
            #pragma unroll
            for (int u = 0; u < WSLOT; ++u){
                const float* base = A.pu + ((long)(b*WSLOT + u)*8)*72;
                si += base[i*72 + lane];
                s7 += base[7*72 + lane];
            }
            float ap = (lane < WSLOT) ? A.pu[((long)(b*WSLOT + lane)*8 + i)*72 + 64] : 0.f;
            #pragma unroll
            for (int m = 1; m < 64; m <<= 1) ap += __shfl_xor(ap, m);
            const float updd = (si + 1e-8f*s7) / (ap + 4.096e-5f);
            const float hprd = slotsb[i][lane];
            ws[lane] = updd; ws[64 + lane] = hprd;
            float gi0 = A.b_ih[lane]     + dot64(ws,    A.W_ih + lane*64);
            float gi1 = A.b_ih[64+lane]  + dot64(ws,    A.W_ih + (64+lane)*64);
            float gi2 = A.b_ih[128+lane] + dot64(ws,    A.W_ih + (128+lane)*64);
            float gh0 = A.b_hh[lane]     + dot64(ws+64, A.W_hh + lane*64);
            float gh1 = A.b_hh[64+lane]  + dot64(ws+64, A.W_hh + (64+lane)*64);
            float gh2 = A.b_hh[128+lane] + dot64(ws+64, A.W_hh + (128+lane)*64);
            float rg = sigm(gi0 + gh0);
            float zg = sigm(gi1 + gh1);
            float ng = tanhf(gi2 + rg*gh2);
            float sn = (1.f - zg)*ng + zg*hprd;
            float s = sn, ssq = sn*sn;
            #pragma unroll
            for (int m = 1; m < 64; m <<= 1){ s += __shfl_xor(s, m); ssq += __shfl_xor(ssq, m); }
            float mean = s * 0.015625f;
            float rstd = rsqrtf(ssq * 0.015625f - mean*mean + 1e-5f);
            float ffd = (sn - mean)*rstd*A.g_ff[lane] + A.be_ff[lane];
            ws[128 + lane] = ffd;
            float ha = A.b1[lane]    + dot64(ws+128, A.W1 + lane*64);
            float hb = A.b1[64+lane] + dot64(ws+128, A.W1 + (64+lane)*64);
            ws[192 + lane] = ha > 0.f ? ha : 0.f;
            ws[256 + lane] = hb > 0.f ? hb : 0.f;
            float o = A.b2[lane] + dot128(ws+192, A.W2 + lane*128);
            float sf = sn + o;
            slotsb[i][lane] = sf;
            if (it == NITER-1){
                if (seg == 0) A.out[(long)(b*NSL + i)*64 + lane] = sf;
            } else {
                float s2v = sf, ss2 = sf*sf;
                #pragma unroll
                for (int m = 1; m < 64; m <<= 1){ s2v += __shfl_xor(s2v, m); ss2 += __shfl_xor(ss2, m); }
                float mean2 = s2v * 0.015625f;
                float rstd2 = rsqrtf(ss2 * 0.015625f - mean2*mean2 + 1e-5f);
                ws[320 + lane] = (sf - mean2)*rstd2*A.g_sl[lane] + A.be_sl[lane];
                qsh[i][lane] = A.bq[lane] + dot64(ws+320, A.Wq + lane*64);
            }
        }
        __syncthreads();   // q ready for all waves next iteration
    }
}

// ---------------------------------------------------------------------------
extern "C" void kernel_launch(void* const* d_in, const int* in_sizes, int n_in,
                              void* d_out, int out_size, void* d_ws, size_t ws_size,
                              hipStream_t stream)
{
    FusedArgs fa;
    fa.inp   = (const float*)d_in[0];
    fa.noise = (const float*)d_in[2];
    fa.mu    = (const float*)d_in[3];
    fa.sigma = (const float*)d_in[4];
    fa.Wq    = (const float*)d_in[5];
    fa.bq    = (const float*)d_in[6];
    fa.Wk    = (const float*)d_in[7];
    fa.bk    = (const float*)d_in[8];
    fa.Wv    = (const float*)d_in[9];
    fa.bv    = (const float*)d_in[10];
    fa.W_ih  = (const float*)d_in[11];
    fa.W_hh  = (const float*)d_in[12];
    fa.b_ih  = (const float*)d_in[13];
    fa.b_hh  = (const float*)d_in[14];
    fa.W1    = (const float*)d_in[15];
    fa.b1    = (const float*)d_in[16];
    fa.W2    = (const float*)d_in[17];
    fa.b2    = (const float*)d_in[18];
    fa.g_in  = (const float*)d_in[19];
    fa.be_in = (const float*)d_in[20];
    fa.g_sl  = (const float*)d_in[21];
    fa.be_sl = (const float*)d_in[22];
    fa.g_ff  = (const float*)d_in[23];
    fa.be_ff = (const float*)d_in[24];
    fa.out   = (float*)d_out;

    char* w = (char*)d_ws;
    fa.pu  = (float*)(w);                        // 64*32*8*72*4 = 4,718,592 B
    fa.ctr = (int*)  (w + 4718592);              // 64*3*4 = 768 B

    hipMemsetAsync(fa.ctr, 0, 64*NITER*sizeof(int), stream);

    void* kargs[] = { (void*)&fa };
    hipError_t e = hipLaunchCooperativeKernel((const void*)fused_kernel,
                                              dim3(512), dim3(256), kargs, 0, stream);
    if (e != hipSuccess){
        fused_kernel<<<512, 256, 0, stream>>>(fa);
    }
}